// Round 2
// baseline (256.575 us; speedup 1.0000x reference)
//
#include <hip/hip_runtime.h>
#include <cstddef>

// Problem constants
#define B_TOT   256
#define IN_CAPS 1152
#define KDIM    8
#define NJ      10
#define ND      16
#define JD      160                 // NJ*ND

// Tiling
#define BB      4                   // batches per block (W register reuse)
#define ISPLIT  16                  // i-splits -> grid = (256/4)*16 = 1024 blocks
#define IRANGE  (IN_CAPS/ISPLIT)    // 72
#define IPAR    8                   // i-parallel groups of 40 threads
#define NTHREADS 320                // IPAR * NJ * 4 = 5 waves
#define CI      IPAR                // i's per chunk (1 per i_par group)
#define NCHUNK  (IRANGE/CI)         // 9
#define GRID    ((B_TOT/BB)*ISPLIT) // 1024

__device__ __forceinline__ float dot4(float4 a, float4 b) {
    return a.x*b.x + a.y*b.y + a.z*b.z + a.w*b.w;
}
__device__ __forceinline__ float getc(const float4& v, int k) {
    switch (k) { case 0: return v.x; case 1: return v.y; case 2: return v.z; default: return v.w; }
}

// One routing iteration. u_hat recomputed from x (LDS, fully staged) and W
// (global, L2-resident per XCD: blockIdx%8 round-robin -> 0.74 MB/XCD).
// !FIRST: c = softmax_j(u_hat . vsum) with logits held in registers; only the
// denominator goes through LDS (2 barriers/chunk). FIRST: no in-loop barriers.
// PARTIAL: plain stores into s_out[isp] slice (block unique per (isp,b-group));
// else: unsafeAtomicAdd fallback into a single slice.
template<bool FIRST, bool PARTIAL>
__global__ __launch_bounds__(NTHREADS, 4)
void iter_kernel(const float* __restrict__ x, const float* __restrict__ Wt,
                 const float* __restrict__ vsum, float* __restrict__ s_out)
{
    const int isp = blockIdx.x & (ISPLIT - 1);
    const int g   = blockIdx.x >> 4;
    const int b0  = g * BB;
    const int i_begin = isp * IRANGE;

    const int t = threadIdx.x;
    const int i_par = t / 40;          // 0..7
    const int r  = t - i_par * 40;
    const int j  = r >> 2;             // 0..9
    const int dq = r & 3;              // 0..3 (owns d = dq*4..dq*4+3)

    __shared__ float4 x_lds[BB][IRANGE][2];    // 9216 B: x[b][i][k] as 2 float4
    __shared__ float  logit_lds[BB][CI][NJ];   // 1280 B
    __shared__ float  denom_lds[BB][CI];       // 128 B (stores reciprocal)
    __shared__ float  s_lds[BB][JD];           // 2560 B

    // stage ALL x for this block: 4 batches x 72 i x 8 k = 576 float4, coalesced
    for (int f = t; f < BB * IRANGE * 2; f += NTHREADS) {
        int bb = f / (IRANGE * 2);
        int fi = f - bb * (IRANGE * 2);
        const float4* src = (const float4*)(x + (size_t)(b0 + bb) * IN_CAPS * KDIM
                                              + (size_t)i_begin * KDIM);
        ((float4*)x_lds)[f] = src[fi];
    }
    for (int e = t; e < BB * JD; e += NTHREADS) ((float*)s_lds)[e] = 0.f;

    float4 vs[BB];
    if (!FIRST) {
        #pragma unroll
        for (int bb = 0; bb < BB; ++bb)
            vs[bb] = *(const float4*)(vsum + (size_t)(b0 + bb) * JD + j * ND + dq * 4);
    }
    __syncthreads();

    float4 s_acc[BB];
    #pragma unroll
    for (int bb = 0; bb < BB; ++bb) s_acc[bb] = make_float4(0.f, 0.f, 0.f, 0.f);

    for (int c = 0; c < NCHUNK; ++c) {
        const int i_loc  = c * CI + i_par;           // local i in [0,72)
        const int i_glob = i_begin + i_loc;
        const float* wrow = Wt + (size_t)(i_glob * NJ + j) * (KDIM * ND) + dq * 4;

        float4 u[BB];
        #pragma unroll
        for (int bb = 0; bb < BB; ++bb) u[bb] = make_float4(0.f, 0.f, 0.f, 0.f);

        #pragma unroll
        for (int kk = 0; kk < 2; ++kk) {             // k halves: keeps x live-range small
            float4 xv[BB];
            #pragma unroll
            for (int bb = 0; bb < BB; ++bb) xv[bb] = x_lds[bb][i_loc][kk];
            #pragma unroll
            for (int k4 = 0; k4 < 4; ++k4) {
                float4 w4 = *(const float4*)(wrow + (kk * 4 + k4) * ND);  // reused x4 batches
                #pragma unroll
                for (int bb = 0; bb < BB; ++bb) {
                    float xs = getc(xv[bb], k4);
                    u[bb].x += xs * w4.x;
                    u[bb].y += xs * w4.y;
                    u[bb].z += xs * w4.z;
                    u[bb].w += xs * w4.w;
                }
            }
        }

        if (FIRST) {
            #pragma unroll
            for (int bb = 0; bb < BB; ++bb) {
                s_acc[bb].x += u[bb].x; s_acc[bb].y += u[bb].y;
                s_acc[bb].z += u[bb].z; s_acc[bb].w += u[bb].w;
            }
        } else {
            float lg[BB];
            #pragma unroll
            for (int bb = 0; bb < BB; ++bb) {
                float l = dot4(u[bb], vs[bb]);
                l += __shfl_xor(l, 1);               // reduce over 4-lane d-quad
                l += __shfl_xor(l, 2);               // all dq lanes now hold full logit
                lg[bb] = l;
                if (dq == 0) logit_lds[bb][i_par][j] = l;
            }
            __syncthreads();
            if (t < BB * CI) {                        // 32 threads: denominators
                int bb = t >> 3, il = t & 7;
                float den = 0.f;
                #pragma unroll
                for (int q = 0; q < NJ; ++q) den += __expf(logit_lds[bb][il][q]);
                denom_lds[bb][il] = 1.0f / den;       // |logit| <~ 3: no max-shift needed
            }
            __syncthreads();
            #pragma unroll
            for (int bb = 0; bb < BB; ++bb) {
                float cc = __expf(lg[bb]) * denom_lds[bb][i_par];
                s_acc[bb].x += cc * u[bb].x; s_acc[bb].y += cc * u[bb].y;
                s_acc[bb].z += cc * u[bb].z; s_acc[bb].w += cc * u[bb].w;
            }
        }
    }

    // block reduction over the 8 i_par groups via LDS atomics (once per kernel)
    const float premul = FIRST ? 0.1f : 1.0f;         // softmax(zeros) over 10 = 0.1
    #pragma unroll
    for (int bb = 0; bb < BB; ++bb) {
        float* dst = &s_lds[bb][j * ND + dq * 4];
        atomicAdd(dst + 0, s_acc[bb].x * premul);
        atomicAdd(dst + 1, s_acc[bb].y * premul);
        atomicAdd(dst + 2, s_acc[bb].z * premul);
        atomicAdd(dst + 3, s_acc[bb].w * premul);
    }
    __syncthreads();
    for (int e = t; e < BB * JD; e += NTHREADS) {     // 640 floats, coalesced
        int bb = e / JD, jd = e - bb * JD;
        float val = s_lds[bb][jd];
        if (PARTIAL)
            s_out[((size_t)isp * B_TOT + b0 + bb) * JD + jd] = val;  // plain store, unique owner
        else
            unsafeAtomicAdd(&s_out[(size_t)(b0 + bb) * JD + jd], val);
    }
}

// squash per (b,j): v = s * s2/(1+s2)/sqrt(s2+eps); 16-lane shuffle reduction.
// P slices of s are summed first. mode 0: vsum = v; 1: vsum += v; 2: out = v.
template<int P>
__global__ __launch_bounds__(256)
void squash_kernel(float* __restrict__ s, float* __restrict__ vsum,
                   float* __restrict__ out, int mode)
{
    int idx = blockIdx.x * 256 + threadIdx.x;        // grid 160 -> 40960
    float sv = 0.f;
    #pragma unroll
    for (int p = 0; p < P; ++p) sv += s[(size_t)p * B_TOT * JD + idx];
    if (P == 1) s[idx] = 0.f;                        // atomic path: re-zero accumulator
    float sq = sv * sv;
    sq += __shfl_xor(sq, 1);
    sq += __shfl_xor(sq, 2);
    sq += __shfl_xor(sq, 4);
    sq += __shfl_xor(sq, 8);                         // sum over 16 d-lanes (16-aligned)
    float scale = sq / (1.0f + sq) / sqrtf(sq + 1e-7f);
    float v = sv * scale;
    if (mode == 0)      vsum[idx] = v;
    else if (mode == 1) vsum[idx] += v;
    else                out[idx] = v;
}

extern "C" void kernel_launch(void* const* d_in, const int* in_sizes, int n_in,
                              void* d_out, int out_size, void* d_ws, size_t ws_size,
                              hipStream_t stream)
{
    const float* x  = (const float*)d_in[0];   // [256,1152,8]
    const float* Wt = (const float*)d_in[1];   // [1152,10,8,16]
    float* out = (float*)d_out;                // [256,10,16]

    dim3 grid(GRID), blk(NTHREADS);
    dim3 sgrid((B_TOT * JD) / 256), sblk(256);

    const size_t slice = (size_t)B_TOT * JD;                    // 40960 floats
    const size_t need  = (ISPLIT + 1) * slice * sizeof(float);  // 2.78 MB

    if (ws_size >= need) {
        // partial-slice path: no atomics, no memset, deterministic
        float* s_part = (float*)d_ws;              // [16][256][160]
        float* vsum   = s_part + ISPLIT * slice;

        iter_kernel<true,  true><<<grid, blk, 0, stream>>>(x, Wt, nullptr, s_part);
        squash_kernel<ISPLIT><<<sgrid, sblk, 0, stream>>>(s_part, vsum, out, 0); // vsum = v1
        iter_kernel<false, true><<<grid, blk, 0, stream>>>(x, Wt, vsum, s_part);
        squash_kernel<ISPLIT><<<sgrid, sblk, 0, stream>>>(s_part, vsum, out, 1); // vsum = v1+v2
        iter_kernel<false, true><<<grid, blk, 0, stream>>>(x, Wt, vsum, s_part);
        squash_kernel<ISPLIT><<<sgrid, sblk, 0, stream>>>(s_part, vsum, out, 2); // out = v3
    } else {
        // fallback: single accumulator slice + global atomics
        float* s    = (float*)d_ws;
        float* vsum = s + slice;
        hipMemsetAsync(d_ws, 0, slice * sizeof(float), stream);

        iter_kernel<true,  false><<<grid, blk, 0, stream>>>(x, Wt, nullptr, s);
        squash_kernel<1><<<sgrid, sblk, 0, stream>>>(s, vsum, out, 0);
        iter_kernel<false, false><<<grid, blk, 0, stream>>>(x, Wt, vsum, s);
        squash_kernel<1><<<sgrid, sblk, 0, stream>>>(s, vsum, out, 1);
        iter_kernel<false, false><<<grid, blk, 0, stream>>>(x, Wt, vsum, s);
        squash_kernel<1><<<sgrid, sblk, 0, stream>>>(s, vsum, out, 2);
    }
}